// Round 1
// baseline (81.002 us; speedup 1.0000x reference)
//
#include <hip/hip_runtime.h>

#define NG 2
#define NV 320
#define GV 640      // NG*NV
#define DHALF 128   // CODE_DIM/NG
#define BSROWS 2048 // B*S
#define NROWS 4096  // BSROWS*NG
#define K_DIM 512

// ---------------- GEMM: logits[2048][640] = x[2048][512] @ W[512][640] + b ----------------
#define BM 64
#define BN 64
#define BK 16

__global__ __launch_bounds__(256) void gemm_bias_kernel(
    const float* __restrict__ A, const float* __restrict__ B,
    const float* __restrict__ bias, float* __restrict__ C) {
  const int N = GV, K = K_DIM;
  __shared__ float As[BK][BM + 4];  // transposed A tile: As[k][m], +4 pad
  __shared__ float Bs[BK][BN + 4];
  const int tid = threadIdx.x;
  const int bx = blockIdx.x;  // over N: 10 tiles
  const int by = blockIdx.y;  // over M: 32 tiles
  const int tx = tid & 15, ty = tid >> 4;

  float acc[4][4] = {};

  // A-load: each thread loads one float4: row = tid>>2 (0..63), k-chunk = (tid&3)*4
  const int arow = tid >> 2;
  const int ac4 = (tid & 3) << 2;
  // B-load: row = tid>>4 (0..15), col-chunk = (tid&15)*4
  const int brow = tid >> 4;
  const int bc4 = (tid & 15) << 2;

  const float* Ag = A + (by * BM + arow) * K + ac4;
  const float* Bg = B + brow * N + bx * BN + bc4;

  for (int k0 = 0; k0 < K; k0 += BK) {
    __syncthreads();
    float4 av = *(const float4*)(Ag + k0);
    float4 bv = *(const float4*)(Bg + k0 * N);
    As[ac4 + 0][arow] = av.x;
    As[ac4 + 1][arow] = av.y;
    As[ac4 + 2][arow] = av.z;
    As[ac4 + 3][arow] = av.w;
    *(float4*)&Bs[brow][bc4] = bv;
    __syncthreads();
#pragma unroll
    for (int kk = 0; kk < BK; ++kk) {
      float4 a = *(const float4*)&As[kk][ty << 2];
      float4 b = *(const float4*)&Bs[kk][tx << 2];
      float ar[4] = {a.x, a.y, a.z, a.w};
      float br[4] = {b.x, b.y, b.z, b.w};
#pragma unroll
      for (int i = 0; i < 4; ++i)
#pragma unroll
        for (int j = 0; j < 4; ++j)
          acc[i][j] = fmaf(ar[i], br[j], acc[i][j]);
    }
  }

  const int crow0 = by * BM + (ty << 2);
  const int ccol = bx * BN + (tx << 2);
  float4 bb = *(const float4*)(bias + ccol);
#pragma unroll
  for (int i = 0; i < 4; ++i) {
    float4 v;
    v.x = acc[i][0] + bb.x;
    v.y = acc[i][1] + bb.y;
    v.z = acc[i][2] + bb.z;
    v.w = acc[i][3] + bb.w;
    *(float4*)(C + (crow0 + i) * N + ccol) = v;
  }
}

// ---------------- Row kernel: per row of [4096,320]: argmax(l+g) + softmax(l) marginals ----
__global__ __launch_bounds__(256) void row_kernel(
    const float* __restrict__ logits, const float* __restrict__ gumbels,
    int* __restrict__ idxOut, float* __restrict__ part) {
  __shared__ float acc[GV];
  const int tid = threadIdx.x;
  for (int i = tid; i < GV; i += 256) acc[i] = 0.f;
  __syncthreads();
  const int lane = tid & 63;
  const int w = tid >> 6;

#pragma unroll 1
  for (int rr = 0; rr < 4; ++rr) {
    const int r = blockIdx.x * 16 + w * 4 + rr;  // row in [0,4096)
    const int bs = r >> 1, g = r & 1;
    const float* lrow = logits + bs * GV + g * NV;
    const float* grow = gumbels + r * NV;
    float lv[5], av[5];
#pragma unroll
    for (int j = 0; j < 5; ++j) {
      lv[j] = lrow[lane + 64 * j];
      av[j] = lv[j] + grow[lane + 64 * j];
    }
    // max of raw logits (softmax stability)
    float m = lv[0];
#pragma unroll
    for (int j = 1; j < 5; ++j) m = fmaxf(m, lv[j]);
#pragma unroll
    for (int o = 32; o > 0; o >>= 1) m = fmaxf(m, __shfl_xor(m, o));
    // exp + sum
    float e[5];
    float s = 0.f;
#pragma unroll
    for (int j = 0; j < 5; ++j) {
      e[j] = expf(lv[j] - m);
      s += e[j];
    }
#pragma unroll
    for (int o = 32; o > 0; o >>= 1) s += __shfl_xor(s, o);
    const float inv = 1.f / s;
    // argmax of l+gumbel, first-index tie-break
    float bv = av[0];
    int bi = lane;
#pragma unroll
    for (int j = 1; j < 5; ++j) {
      if (av[j] > bv) { bv = av[j]; bi = lane + 64 * j; }
    }
#pragma unroll
    for (int o = 32; o > 0; o >>= 1) {
      float ov = __shfl_xor(bv, o);
      int oi = __shfl_xor(bi, o);
      if (ov > bv || (ov == bv && oi < bi)) { bv = ov; bi = oi; }
    }
    if (lane == 0) idxOut[r] = bi;
    // accumulate normalized softmax into per-block marginal partials
#pragma unroll
    for (int j = 0; j < 5; ++j)
      atomicAdd(&acc[g * NV + lane + 64 * j], e[j] * inv);
  }
  __syncthreads();
  for (int i = tid; i < GV; i += 256)
    part[blockIdx.x * GV + i] = acc[i];
}

// ---------------- Gather: out[bs, g*128+d] = codevectors[(g*320+idx[bs,g])*128 + d] --------
__global__ __launch_bounds__(256) void gather_kernel(
    const int* __restrict__ idx, const float* __restrict__ cvs,
    float* __restrict__ out) {
  const int q = blockIdx.x * 256 + threadIdx.x;  // float4 index, 0..131071
  const int f = q << 2;
  const int bs = f >> 8;
  const int rem = f & 255;
  const int g = rem >> 7;
  const int d = rem & 127;
  const int id = idx[(bs << 1) + g];
  const float4 v = *(const float4*)(cvs + (g * NV + id) * DHALF + d);
  *(float4*)(out + f) = v;
}

// ---------------- Perplexity: reduce partials -> marg -> sum exp(entropy) ------------------
__global__ __launch_bounds__(256) void perp_kernel(
    const float* __restrict__ part, float* __restrict__ perpOut) {
  __shared__ float colsum[GV];
  const int tid = threadIdx.x;
  for (int i = tid; i < GV; i += 256) {
    float s = 0.f;
    for (int b = 0; b < 256; ++b) s += part[b * GV + i];
    colsum[i] = s;
  }
  __syncthreads();
  float h0 = 0.f, h1 = 0.f;
  for (int i = tid; i < GV; i += 256) {
    const float mmean = colsum[i] * (1.0f / BSROWS);
    const float t = mmean * logf(mmean + 1e-7f);
    if (i < NV) h0 += t; else h1 += t;
  }
  __shared__ float r0[256], r1[256];
  r0[tid] = h0;
  r1[tid] = h1;
  __syncthreads();
  for (int s = 128; s > 0; s >>= 1) {
    if (tid < s) { r0[tid] += r0[tid + s]; r1[tid] += r1[tid + s]; }
    __syncthreads();
  }
  if (tid == 0) perpOut[0] = expf(-r0[0]) + expf(-r1[0]);
}

extern "C" void kernel_launch(void* const* d_in, const int* in_sizes, int n_in,
                              void* d_out, int out_size, void* d_ws, size_t ws_size,
                              hipStream_t stream) {
  const float* x = (const float*)d_in[0];
  const float* W = (const float*)d_in[1];
  const float* b = (const float*)d_in[2];
  const float* cvs = (const float*)d_in[3];
  const float* gum = (const float*)d_in[4];
  float* out = (float*)d_out;

  float* logits = (float*)d_ws;                 // 2048*640 floats
  int* idx = (int*)(logits + BSROWS * GV);      // 4096 ints
  float* part = (float*)(idx + NROWS);          // 256*640 floats

  dim3 ggrid(GV / BN, BSROWS / BM);  // (10, 32)
  gemm_bias_kernel<<<ggrid, 256, 0, stream>>>(x, W, b, logits);
  row_kernel<<<NROWS / 16, 256, 0, stream>>>(logits, gum, idx, part);
  gather_kernel<<<(BSROWS * 256 / 4) / 256, 256, 0, stream>>>(idx, cvs, out);
  perp_kernel<<<1, 256, 0, stream>>>(part, out + BSROWS * 256);
}